// Round 13
// baseline (182.938 us; speedup 1.0000x reference)
//
#include <hip/hip_runtime.h>
#include <hip/hip_bf16.h>
#include <math.h>

#define NIN      128
#define NCLS     10
#define NNODES   255
#define TSAMP    65536

#define MBLK     16                 // samples per block = one wave
#define NBLOCKS  (TSAMP / MBLK)     // 4096

typedef short bf16x8  __attribute__((ext_vector_type(8)));
typedef short short4v __attribute__((ext_vector_type(4)));
typedef float f32x4   __attribute__((ext_vector_type(4)));

// d_ws layout (bytes):
//   [0,     65280)  Wbf : bf16 (beta*log2e)-scaled W, row-major 255x128
//   [65280, 66304)  bb  : f32[256] = beta*b*log2e
//   [66304, 66816)  rd  : f32[128] = r[2t] - r[2t+1]
//   [66816, 67328)  r1  : f32[128] = r[2t+1]
#define WS_BB  65280
#define WS_RD  66304
#define WS_R1  66816

#define LOG2E  1.44269504088896f

__device__ __forceinline__ short f2b(float f) {
    return __builtin_bit_cast(short, __float2bfloat16(f));   // RNE hw cvt
}
__device__ __forceinline__ float b2f(short h) {
    return __builtin_bit_cast(float, ((unsigned)(unsigned short)h) << 16);
}
__device__ __forceinline__ bf16x8 mk8(float4 a, float4 b) {
    bf16x8 r;
    r[0] = f2b(a.x); r[1] = f2b(a.y); r[2] = f2b(a.z); r[3] = f2b(a.w);
    r[4] = f2b(b.x); r[5] = f2b(b.y); r[6] = f2b(b.z); r[7] = f2b(b.w);
    return r;
}
// bijective node relabel: spreads the 4 tree-quarters (node spacing 32) across
// disjoint 8-bank groups of the 32-byte Lg rows -> ~conflict-free ds_read_u16
__device__ __forceinline__ int perm(int n) { return n ^ ((n >> 5) & 3); }

// ---- prep: fold beta*log2e into W (bf16) and b; leaf reward pairs ----
extern "C" __global__ void __launch_bounds__(128)
sdt_prep(const float* __restrict__ W, const float* __restrict__ b,
         const float* __restrict__ beta, const float* __restrict__ leaf_dist,
         const float* __restrict__ cr, char* __restrict__ ws) {
    short* Wbf = (short*)ws;
    float* bb  = (float*)(ws + WS_BB);
    float* rd  = (float*)(ws + WS_RD);
    float* r1  = (float*)(ws + WS_R1);
    const int n = blockIdx.x;       // 0..255
    const int t = threadIdx.x;      // 0..127
    if (n < NNODES) {
        const float be = beta[n] * LOG2E;
        Wbf[n * NIN + t] = f2b(W[n * NIN + t] * be);
        if (t == 0) bb[n] = be * b[n];
    } else {
        float rv[2];
        #pragma unroll
        for (int h = 0; h < 2; ++h) {
            const float* ld = leaf_dist + (size_t)(2 * t + h) * NCLS;
            float mx = -1e30f, v[NCLS];
            #pragma unroll
            for (int c = 0; c < NCLS; ++c) { v[c] = ld[c]; mx = fmaxf(mx, v[c]); }
            float s = 0.f, d = 0.f;
            #pragma unroll
            for (int c = 0; c < NCLS; ++c) { float e = __expf(v[c] - mx); s += e; d += e * cr[c]; }
            rv[h] = __fdividef(d, s);
        }
        rd[t] = rv[0] - rv[1];
        r1[t] = rv[1];
    }
}

// ---- main: one wave per 16 samples; no cross-wave sync ----
extern "C" __global__ void __launch_bounds__(64, 4)
sdt_main(const float* __restrict__ x, const char* __restrict__ ws,
         float* __restrict__ out) {
    __shared__ short Lg[256 * 16];   // [perm(node)][sample] bf16 logits (8 KB)
    __shared__ float bbS[256];
    __shared__ float rdS[128];
    __shared__ float r1S[128];

    const short* Wbf  = (const short*)ws;
    const float* g_bb = (const float*)(ws + WS_BB);
    const float* g_rd = (const float*)(ws + WS_RD);
    const float* g_r1 = (const float*)(ws + WS_R1);

    const int tid = threadIdx.x;     // 0..63 (one wave)
    const int r16 = tid & 15;
    const int kg  = tid >> 4;

    // ---- stage small tables (64 float4 bb, 32+32 float4 rd/r1) ----
    ((float4*)bbS)[tid] = ((const float4*)g_bb)[tid];
    if (tid < 32) ((float4*)rdS)[tid] = ((const float4*)g_rd)[tid];
    else          ((float4*)r1S)[tid - 32] = ((const float4*)g_r1)[tid - 32];

    // ---- GEMM: 16 samples x 256 nodes, bf16 MFMA 16x16x32 ----
    const int m0 = blockIdx.x * MBLK;
    const float4* ap = (const float4*)(x + (size_t)(m0 + r16) * NIN + kg * 8);

    bf16x8 af[4];
    #pragma unroll
    for (int ks = 0; ks < 4; ++ks) af[ks] = mk8(ap[ks * 8], ap[ks * 8 + 1]);

    f32x4 acc[16];
    #pragma unroll
    for (int i = 0; i < 16; ++i) acc[i] = (f32x4){0.f, 0.f, 0.f, 0.f};

    #pragma unroll 4
    for (int nf = 0; nf < 16; ++nf) {
        int node = nf * 16 + r16;
        int nd   = (node > 254) ? 254 : node;          // clamp (benign dup)
        const bf16x8* bp = (const bf16x8*)(Wbf + (size_t)nd * NIN);
        #pragma unroll
        for (int ks = 0; ks < 4; ++ks)
            acc[nf] = __builtin_amdgcn_mfma_f32_16x16x32_bf16(
                af[ks], bp[kg + ks * 4], acc[nf], 0, 0, 0);
    }

    // C/D: col(node)=lane&15, row(sample)=kg*4+reg -> 4 consecutive samples
    #pragma unroll
    for (int nf = 0; nf < 16; ++nf) {
        int node = nf * 16 + r16;
        int nd   = (node > 254) ? 254 : node;
        short4v hv;
        hv[0] = f2b(acc[nf][0]); hv[1] = f2b(acc[nf][1]);
        hv[2] = f2b(acc[nf][2]); hv[3] = f2b(acc[nf][3]);
        *(short4v*)&Lg[perm(nd) * 16 + kg * 4] = hv;
    }
    __syncthreads();   // single-wave barrier: just a waitcnt, cheap

    // ---- tree: thread = (sample s = tid&15, quarter g = tid>>4) ----
    const int s = tid & 15;
    const int g = tid >> 4;

    auto SIG = [&](int node, int smp) -> float {
        float t = b2f(Lg[perm(node) * 16 + smp]) + bbS[node];
        // t is pre-scaled by log2e; exp2f lowers to native v_exp_f32 (2^x)
        return __fdividef(1.f, 1.f + exp2f(-t));
    };

    float v7[32];
    #pragma unroll
    for (int i = 0; i < 32; ++i) {
        float p = SIG(127 + 32 * g + i, s);
        v7[i] = fmaf(p, rdS[32 * g + i], r1S[32 * g + i]);
    }
    float v6[16];
    #pragma unroll
    for (int i = 0; i < 16; ++i) {
        float p = SIG(63 + 16 * g + i, s);
        v6[i] = fmaf(p, v7[2 * i] - v7[2 * i + 1], v7[2 * i + 1]);
    }
    float v5[8];
    #pragma unroll
    for (int i = 0; i < 8; ++i) {
        float p = SIG(31 + 8 * g + i, s);
        v5[i] = fmaf(p, v6[2 * i] - v6[2 * i + 1], v6[2 * i + 1]);
    }
    float v4[4];
    #pragma unroll
    for (int i = 0; i < 4; ++i) {
        float p = SIG(15 + 4 * g + i, s);
        v4[i] = fmaf(p, v5[2 * i] - v5[2 * i + 1], v5[2 * i + 1]);
    }
    float v3[2];
    #pragma unroll
    for (int i = 0; i < 2; ++i) {
        float p = SIG(7 + 2 * g + i, s);
        v3[i] = fmaf(p, v4[2 * i] - v4[2 * i + 1], v4[2 * i + 1]);
    }
    float v2;
    {
        float p = SIG(3 + g, s);
        v2 = fmaf(p, v3[0] - v3[1], v3[1]);
    }

    // ---- in-wave final combine: gather the 4 quarters of sample s ----
    float a0 = __shfl(v2, s);
    float a1 = __shfl(v2, s + 16);
    float a2 = __shfl(v2, s + 32);
    float a3 = __shfl(v2, s + 48);
    float p0 = SIG(0, s);
    float p1 = SIG(1, s);
    float p2 = SIG(2, s);
    float L  = fmaf(p1, a0 - a1, a1);
    float R  = fmaf(p2, a2 - a3, a3);
    float val = fmaf(p0, L - R, R);
    if (g != 0) val = 0.f;           // quarters computed identical finals; keep one

    #pragma unroll
    for (int off = 32; off > 0; off >>= 1) val += __shfl_down(val, off);
    if (tid == 0) atomicAdd(out, val);
}

extern "C" void kernel_launch(void* const* d_in, const int* in_sizes, int n_in,
                              void* d_out, int out_size, void* d_ws, size_t ws_size,
                              hipStream_t stream) {
    const float* x            = (const float*)d_in[0];
    const float* W            = (const float*)d_in[1];
    const float* b            = (const float*)d_in[2];
    const float* beta         = (const float*)d_in[3];
    const float* leaf_dist    = (const float*)d_in[4];
    const float* class_reward = (const float*)d_in[5];
    float* out = (float*)d_out;

    hipMemsetAsync(d_out, 0, sizeof(float), stream);

    sdt_prep<<<256, 128, 0, stream>>>(W, b, beta, leaf_dist, class_reward,
                                      (char*)d_ws);
    sdt_main<<<NBLOCKS, 64, 0, stream>>>(x, (const char*)d_ws, out);
}

// Round 14
// 165.530 us; speedup vs baseline: 1.1052x; 1.1052x over previous
//
#include <hip/hip_runtime.h>
#include <hip/hip_bf16.h>
#include <math.h>

#define NIN      128
#define NCLS     10
#define NNODES   255
#define TSAMP    65536

#define MBLK     16                 // samples per block = one wave
#define NBLOCKS  (TSAMP / MBLK)     // 4096

typedef short bf16x8  __attribute__((ext_vector_type(8)));
typedef short short4v __attribute__((ext_vector_type(4)));
typedef float f32x4   __attribute__((ext_vector_type(4)));

// d_ws layout (bytes):
//   [0,     65280)  Wbf : bf16 (beta*log2e)-scaled W, row-major 255x128
//   [65280, 66304)  bb  : f32[256] = beta*b*log2e
//   [66304, 66816)  rd  : f32[128] = r[2t] - r[2t+1]
//   [66816, 67328)  r1  : f32[128] = r[2t+1]
#define WS_BB  65280
#define WS_RD  66304
#define WS_R1  66816

#define LOG2E  1.44269504088896f

__device__ __forceinline__ short f2b(float f) {
    return __builtin_bit_cast(short, __float2bfloat16(f));   // RNE hw cvt
}
__device__ __forceinline__ float b2f(short h) {
    return __builtin_bit_cast(float, ((unsigned)(unsigned short)h) << 16);
}
__device__ __forceinline__ bf16x8 mk8(float4 a, float4 b) {
    bf16x8 r;
    r[0] = f2b(a.x); r[1] = f2b(a.y); r[2] = f2b(a.z); r[3] = f2b(a.w);
    r[4] = f2b(b.x); r[5] = f2b(b.y); r[6] = f2b(b.z); r[7] = f2b(b.w);
    return r;
}
// bijective node relabel: spreads the 4 tree-quarters (node spacing 32) across
// disjoint 8-bank groups of the 32-byte Lg rows -> ~conflict-free ds_read_u16
__device__ __forceinline__ int perm(int n) { return n ^ ((n >> 5) & 3); }

// ---- prep: fold beta*log2e into W (bf16) and b; leaf reward pairs ----
extern "C" __global__ void __launch_bounds__(128)
sdt_prep(const float* __restrict__ W, const float* __restrict__ b,
         const float* __restrict__ beta, const float* __restrict__ leaf_dist,
         const float* __restrict__ cr, char* __restrict__ ws) {
    short* Wbf = (short*)ws;
    float* bb  = (float*)(ws + WS_BB);
    float* rd  = (float*)(ws + WS_RD);
    float* r1  = (float*)(ws + WS_R1);
    const int n = blockIdx.x;       // 0..255
    const int t = threadIdx.x;      // 0..127
    if (n < NNODES) {
        const float be = beta[n] * LOG2E;
        Wbf[n * NIN + t] = f2b(W[n * NIN + t] * be);
        if (t == 0) bb[n] = be * b[n];
    } else {
        float rv[2];
        #pragma unroll
        for (int h = 0; h < 2; ++h) {
            const float* ld = leaf_dist + (size_t)(2 * t + h) * NCLS;
            float mx = -1e30f, v[NCLS];
            #pragma unroll
            for (int c = 0; c < NCLS; ++c) { v[c] = ld[c]; mx = fmaxf(mx, v[c]); }
            float s = 0.f, d = 0.f;
            #pragma unroll
            for (int c = 0; c < NCLS; ++c) { float e = __expf(v[c] - mx); s += e; d += e * cr[c]; }
            rv[h] = __fdividef(d, s);
        }
        rd[t] = rv[0] - rv[1];
        r1[t] = rv[1];
    }
}

// ---- main: one wave per 16 samples; no cross-wave sync ----
extern "C" __global__ void __launch_bounds__(64, 4)
sdt_main(const float* __restrict__ x, const char* __restrict__ ws,
         float* __restrict__ out) {
    __shared__ short Lg[256 * 16];   // [perm(node)][sample] bf16 logits (8 KB)
    __shared__ float bbS[256];
    __shared__ float rdS[128];
    __shared__ float r1S[128];

    const short* Wbf  = (const short*)ws;
    const float* g_bb = (const float*)(ws + WS_BB);
    const float* g_rd = (const float*)(ws + WS_RD);
    const float* g_r1 = (const float*)(ws + WS_R1);

    const int tid = threadIdx.x;     // 0..63 (one wave)
    const int r16 = tid & 15;
    const int kg  = tid >> 4;

    // ---- stage small tables (64 float4 bb, 32+32 float4 rd/r1) ----
    ((float4*)bbS)[tid] = ((const float4*)g_bb)[tid];
    if (tid < 32) ((float4*)rdS)[tid] = ((const float4*)g_rd)[tid];
    else          ((float4*)r1S)[tid - 32] = ((const float4*)g_r1)[tid - 32];

    // ---- GEMM: 16 samples x 256 nodes, bf16 MFMA 16x16x32 ----
    const int m0 = blockIdx.x * MBLK;
    const float4* ap = (const float4*)(x + (size_t)(m0 + r16) * NIN + kg * 8);

    bf16x8 af[4];
    #pragma unroll
    for (int ks = 0; ks < 4; ++ks) af[ks] = mk8(ap[ks * 8], ap[ks * 8 + 1]);

    f32x4 acc[16];
    #pragma unroll
    for (int i = 0; i < 16; ++i) acc[i] = (f32x4){0.f, 0.f, 0.f, 0.f};

    // FULLY unrolled: acc[nf] must be a compile-time index (rule #20 —
    // "#pragma unroll 4" here spilled acc to scratch: VGPR=52, 131 MB scratch writes)
    #pragma unroll
    for (int nf = 0; nf < 16; ++nf) {
        int node = nf * 16 + r16;
        int nd   = (node > 254) ? 254 : node;          // clamp (benign dup)
        const bf16x8* bp = (const bf16x8*)(Wbf + (size_t)nd * NIN);
        #pragma unroll
        for (int ks = 0; ks < 4; ++ks)
            acc[nf] = __builtin_amdgcn_mfma_f32_16x16x32_bf16(
                af[ks], bp[kg + ks * 4], acc[nf], 0, 0, 0);
    }

    // C/D: col(node)=lane&15, row(sample)=kg*4+reg -> 4 consecutive samples
    #pragma unroll
    for (int nf = 0; nf < 16; ++nf) {
        int node = nf * 16 + r16;
        int nd   = (node > 254) ? 254 : node;
        short4v hv;
        hv[0] = f2b(acc[nf][0]); hv[1] = f2b(acc[nf][1]);
        hv[2] = f2b(acc[nf][2]); hv[3] = f2b(acc[nf][3]);
        *(short4v*)&Lg[perm(nd) * 16 + kg * 4] = hv;
    }
    __syncthreads();   // single-wave barrier: just a waitcnt, cheap

    // ---- tree: thread = (sample s = tid&15, quarter g = tid>>4) ----
    const int s = tid & 15;
    const int g = tid >> 4;

    auto SIG = [&](int node, int smp) -> float {
        float t = b2f(Lg[perm(node) * 16 + smp]) + bbS[node];
        // t is pre-scaled by log2e; exp2f lowers to native v_exp_f32 (2^x)
        return __fdividef(1.f, 1.f + exp2f(-t));
    };

    float v7[32];
    #pragma unroll
    for (int i = 0; i < 32; ++i) {
        float p = SIG(127 + 32 * g + i, s);
        v7[i] = fmaf(p, rdS[32 * g + i], r1S[32 * g + i]);
    }
    float v6[16];
    #pragma unroll
    for (int i = 0; i < 16; ++i) {
        float p = SIG(63 + 16 * g + i, s);
        v6[i] = fmaf(p, v7[2 * i] - v7[2 * i + 1], v7[2 * i + 1]);
    }
    float v5[8];
    #pragma unroll
    for (int i = 0; i < 8; ++i) {
        float p = SIG(31 + 8 * g + i, s);
        v5[i] = fmaf(p, v6[2 * i] - v6[2 * i + 1], v6[2 * i + 1]);
    }
    float v4[4];
    #pragma unroll
    for (int i = 0; i < 4; ++i) {
        float p = SIG(15 + 4 * g + i, s);
        v4[i] = fmaf(p, v5[2 * i] - v5[2 * i + 1], v5[2 * i + 1]);
    }
    float v3[2];
    #pragma unroll
    for (int i = 0; i < 2; ++i) {
        float p = SIG(7 + 2 * g + i, s);
        v3[i] = fmaf(p, v4[2 * i] - v4[2 * i + 1], v4[2 * i + 1]);
    }
    float v2;
    {
        float p = SIG(3 + g, s);
        v2 = fmaf(p, v3[0] - v3[1], v3[1]);
    }

    // ---- in-wave final combine: gather the 4 quarters of sample s ----
    float a0 = __shfl(v2, s);
    float a1 = __shfl(v2, s + 16);
    float a2 = __shfl(v2, s + 32);
    float a3 = __shfl(v2, s + 48);
    float p0 = SIG(0, s);
    float p1 = SIG(1, s);
    float p2 = SIG(2, s);
    float L  = fmaf(p1, a0 - a1, a1);
    float R  = fmaf(p2, a2 - a3, a3);
    float val = fmaf(p0, L - R, R);
    if (g != 0) val = 0.f;           // quarters computed identical finals; keep one

    #pragma unroll
    for (int off = 32; off > 0; off >>= 1) val += __shfl_down(val, off);
    if (tid == 0) atomicAdd(out, val);
}

extern "C" void kernel_launch(void* const* d_in, const int* in_sizes, int n_in,
                              void* d_out, int out_size, void* d_ws, size_t ws_size,
                              hipStream_t stream) {
    const float* x            = (const float*)d_in[0];
    const float* W            = (const float*)d_in[1];
    const float* b            = (const float*)d_in[2];
    const float* beta         = (const float*)d_in[3];
    const float* leaf_dist    = (const float*)d_in[4];
    const float* class_reward = (const float*)d_in[5];
    float* out = (float*)d_out;

    hipMemsetAsync(d_out, 0, sizeof(float), stream);

    sdt_prep<<<256, 128, 0, stream>>>(W, b, beta, leaf_dist, class_reward,
                                      (char*)d_ws);
    sdt_main<<<NBLOCKS, 64, 0, stream>>>(x, (const char*)d_ws, out);
}